// Round 3
// baseline (1995.571 us; speedup 1.0000x reference)
//
#include <hip/hip_runtime.h>
#include <math.h>

typedef unsigned long long u64;
typedef unsigned int u32;

#define TOTE      273024      // 2 * 136512 score elements
#define BTOT      136512
#define NDET      4448        // 1000*4 + 448
#define NW        70          // ceil(4448/64)
#define SC_BASE   35584       // 2*4448*4
#define LAB_BASE  44480
#define KEEP_BASE 53376
#define CAND_CAP  8192

struct Ptrs {
  const float* loc[5];
  const float* cls[5];
  const float* box[5];
  const float* ctr[5];
};

__constant__ int c_HW[5]  = {12800, 3200, 800, 208, 56};
__constant__ int c_K[5]   = {1000, 1000, 1000, 1000, 448};
__constant__ int c_OFF[5] = {0, 1000, 2000, 3000, 4000};

// XLA LogisticExpander: logistic(x) = 1 / (1 + exp(-x)).
// expf() == __ocml_exp_f32 on ROCm -> bit-identical to a jax-rocm reference.
__device__ __forceinline__ float ref_sigmoid(float x) {
#pragma clang fp contract(off)
  float e = expf(-x);
  return 1.0f / (1.0f + e);
}

__device__ __forceinline__ u32 ordf(float v) {
  u32 b = __float_as_uint(v);
  return (b & 0x80000000u) ? ~b : (b | 0x80000000u);
}
__device__ __forceinline__ float unordf(u32 o) {
  u32 b = (o & 0x80000000u) ? (o ^ 0x80000000u) : ~o;
  return __uint_as_float(b);
}

__device__ __forceinline__ u64 shfl64(u64 v, int src) {
  int lo = __shfl((int)(u32)(v & 0xFFFFFFFFull), src, 64);
  int hi = __shfl((int)(u32)(v >> 32), src, 64);
  return ((u64)(u32)hi << 32) | (u32)lo;
}

// element id -> (segment = b*5+l, local flat index f within segment)
__device__ __forceinline__ int seg_decompose(int e, int& f) {
  int b = 0;
  if (e >= BTOT) { b = 1; e -= BTOT; }
  int l, base;
  if      (e < 102400) { l = 0; base = 0; }
  else if (e < 128000) { l = 1; base = 102400; }
  else if (e < 134400) { l = 2; base = 128000; }
  else if (e < 136064) { l = 3; base = 134400; }
  else                 { l = 4; base = 136064; }
  f = e - base;
  return b * 5 + l;
}

__global__ __launch_bounds__(256) void k_zero(u32* hist, u32* cnt) {
  int i = blockIdx.x * 256 + threadIdx.x;
  if (i < 10 * 65536) hist[i] = 0u;
  if (i < 16) cnt[i] = 0u;
}

__global__ __launch_bounds__(256) void k_keys_hist(Ptrs p, u64* keyb, u32* hist) {
#pragma clang fp contract(off)
  int e = blockIdx.x * 256 + threadIdx.x;
  if (e >= TOTE) return;
  int f; int s = seg_decompose(e, f);
  int b = s / 5, l = s % 5;
  int hw = f >> 3, c = f & 7;
  int HW = c_HW[l];
  float cp = ref_sigmoid(p.cls[l][(size_t)(b * 8 + c) * HW + hw]);
  float flatv = -1.0f;
  if (cp > 0.05f) {
    float tp = ref_sigmoid(p.ctr[l][(size_t)b * HW + hw]);
    flatv = cp * tp;   // score = cls_p * ctr_p
  }
  u32 o = ordf(flatv);
  keyb[e] = ((u64)o << 32) | (0xFFFFFFFFu - (u32)f);  // desc value, asc idx
  atomicAdd(&hist[(s << 16) + (o >> 16)], 1u);
}

__global__ __launch_bounds__(256) void k_select(const u32* hist, u32* cut) {
  __shared__ u32 cs[256];
  int s = blockIdx.x, tid = threadIdx.x;
  const u32* h = hist + (s << 16);
  u32 sum = 0;
  for (int i = 0; i < 256; ++i) sum += h[tid * 256 + i];
  cs[tid] = sum;
  __syncthreads();
  if (tid == 0) {
    u32 k = (u32)c_K[s % 5];
    u32 cum = 0; int bstar = 0;
    for (int ch = 255; ch >= 0; --ch) {
      if (cum + cs[ch] >= k) {
        for (int bb = 255; bb >= 0; --bb) {
          u32 c2 = h[ch * 256 + bb];
          if (cum + c2 >= k) { bstar = ch * 256 + bb; break; }
          cum += c2;
        }
        break;
      }
      cum += cs[ch];
    }
    cut[s] = (u32)bstar;
  }
}

__global__ __launch_bounds__(256) void k_gather(const u64* keyb, const u32* cut,
                                                u32* cnt, u64* cand) {
  int e = blockIdx.x * 256 + threadIdx.x;
  if (e >= TOTE) return;
  int f; int s = seg_decompose(e, f);
  u64 key = keyb[e];
  u32 bin = (u32)(key >> 48);
  if (bin >= cut[s]) {
    u32 pos = atomicAdd(&cnt[s], 1u);
    if (pos < CAND_CAP) cand[((size_t)s << 13) + pos] = key;
  }
}

__device__ __forceinline__ void bitonic8192_desc(u64* sb, int tid, int nthr) {
  for (u32 k = 2; k <= 8192; k <<= 1) {
    for (u32 j = k >> 1; j > 0; j >>= 1) {
      __syncthreads();
      for (u32 i = (u32)tid; i < 8192; i += (u32)nthr) {
        u32 l = i ^ j;
        if (l > i) {
          u64 a = sb[i], b = sb[l];
          bool up = ((i & k) != 0);           // inverted -> final descending
          if (up ? (a > b) : (a < b)) { sb[i] = b; sb[l] = a; }
        }
      }
    }
  }
  __syncthreads();
}

extern __shared__ u64 sbuf[];

__global__ __launch_bounds__(1024) void k_sortdecode(Ptrs p, const u64* cand, const u32* cnt,
                             float* px1, float* py1, float* px2, float* py2,
                             float* psc, int* plab, int* pval) {
#pragma clang fp contract(off)
  int s = blockIdx.x, tid = threadIdx.x;
  int b = s / 5, l = s % 5;
  int n = (int)cnt[s]; if (n > CAND_CAP) n = CAND_CAP;
  for (int i = tid; i < 8192; i += 1024)
    sbuf[i] = (i < n) ? cand[((size_t)s << 13) + i] : 0ull;
  __syncthreads();
  bitonic8192_desc(sbuf, tid, 1024);
  int k = c_K[l], off = c_OFF[l], HW = c_HW[l];
  for (int r = tid; r < k; r += 1024) {
    int pos = b * NDET + off + r;
    if (r < n) {
      u64 key = sbuf[r];
      float val = unordf((u32)(key >> 32));
      u32 f = 0xFFFFFFFFu - (u32)(key & 0xFFFFFFFFull);
      int hw = (int)(f >> 3), c = (int)(f & 7);
      float x = p.loc[l][hw * 2 + 0], y = p.loc[l][hw * 2 + 1];
      float b0 = p.box[l][(size_t)(b * 4 + 0) * HW + hw];
      float b1 = p.box[l][(size_t)(b * 4 + 1) * HW + hw];
      float b2 = p.box[l][(size_t)(b * 4 + 2) * HW + hw];
      float b3 = p.box[l][(size_t)(b * 4 + 3) * HW + hw];
      float d0 = x - b0, d1 = y - b1, d2 = x + b2, d3 = y + b3;
      float x1 = fminf(fmaxf(d0, 0.0f), 1023.0f);   // clip to [0, W-1]
      float y1 = fminf(fmaxf(d1, 0.0f), 799.0f);    // clip to [0, H-1]
      float x2 = fminf(fmaxf(d2, 0.0f), 1023.0f);
      float y2 = fminf(fmaxf(d3, 0.0f), 799.0f);
      int valid = (val > 0.0f) ? 1 : 0;
      if (!((x2 - x1 + 1.0f) >= 0.0f) || !((y2 - y1 + 1.0f) >= 0.0f)) valid = 0;
      float sc = valid ? sqrtf(val) : 0.0f;
      px1[pos] = x1; py1[pos] = y1; px2[pos] = x2; py2[pos] = y2;
      psc[pos] = sc; plab[pos] = c + 1; pval[pos] = valid;
    } else {
      px1[pos] = 0.f; py1[pos] = 0.f; px2[pos] = 0.f; py2[pos] = 0.f;
      psc[pos] = 0.f; plab[pos] = 1; pval[pos] = 0;
    }
  }
}

__global__ __launch_bounds__(1024) void k_globalsort(const float* px1, const float* py1,
                             const float* px2, const float* py2,
                             const float* psc, const int* plab, const int* pval,
                             float* out, float* ssc, int* sval,
                             float* ox1, float* oy1, float* ox2, float* oy2, float* oarea) {
#pragma clang fp contract(off)
  int b = blockIdx.x, tid = threadIdx.x;
  for (int i = tid; i < 8192; i += 1024) {
    u64 key = 0ull;
    if (i < NDET) {
      int g = b * NDET + i;
      float v = pval[g] ? psc[g] : -1.0f;   // argsort(-where(valid, sc, -1)), stable
      key = ((u64)ordf(v) << 32) | (0xFFFFFFFFu - (u32)i);
    }
    sbuf[i] = key;
  }
  __syncthreads();
  bitonic8192_desc(sbuf, tid, 1024);
  for (int r = tid; r < NDET; r += 1024) {
    u64 key = sbuf[r];
    int g = (int)(0xFFFFFFFFu - (u32)(key & 0xFFFFFFFFull));
    int src = b * NDET + g, dst = b * NDET + r;
    float x1 = px1[src], y1 = py1[src], x2 = px2[src], y2 = py2[src];
    out[(size_t)dst * 4 + 0] = x1;
    out[(size_t)dst * 4 + 1] = y1;
    out[(size_t)dst * 4 + 2] = x2;
    out[(size_t)dst * 4 + 3] = y2;
    float labf = (float)plab[src];
    out[LAB_BASE + dst] = labf;
    ssc[dst] = psc[src];
    sval[dst] = pval[src];
    float a1 = x1 + labf * 4096.0f;   // bo = boxes + label*CLASS_OFFSET (no fma!)
    float c1 = y1 + labf * 4096.0f;
    float a2 = x2 + labf * 4096.0f;
    float c2 = y2 + labf * 4096.0f;
    ox1[dst] = a1; oy1[dst] = c1; ox2[dst] = a2; oy2[dst] = c2;
    oarea[dst] = (a2 - a1) * (c2 - c1);
  }
}

__global__ __launch_bounds__(64) void k_mask(const float* ox1, const float* oy1,
                       const float* ox2, const float* oy2,
                       const float* oarea, u64* mask) {
#pragma clang fp contract(off)
  int w = blockIdx.x, ti = blockIdx.y, b = blockIdx.z;
  if (w < ti) return;                       // j <= i tiles never read
  int lane = threadIdx.x;
  __shared__ float cx1[64], cy1[64], cx2[64], cy2[64], car[64];
  int j0 = w * 64;
  int j = j0 + lane;
  if (j < NDET) {
    int g = b * NDET + j;
    cx1[lane] = ox1[g]; cy1[lane] = oy1[g];
    cx2[lane] = ox2[g]; cy2[lane] = oy2[g];
    car[lane] = oarea[g];
  }
  __syncthreads();
  int i = ti * 64 + lane;
  if (i >= NDET) return;
  int g = b * NDET + i;
  float rx1 = ox1[g], ry1 = oy1[g], rx2 = ox2[g], ry2 = oy2[g], ra = oarea[g];
  u64 m = 0ull;
  int jmax = NDET - j0; if (jmax > 64) jmax = 64;
  for (int jj = 0; jj < jmax; ++jj) {
    int jg = j0 + jj;
    if (jg > i) {
      float xx1 = fmaxf(rx1, cx1[jj]);
      float yy1 = fmaxf(ry1, cy1[jj]);
      float xx2 = fminf(rx2, cx2[jj]);
      float yy2 = fminf(ry2, cy2[jj]);
      float iw = fmaxf(xx2 - xx1, 0.0f);
      float ih = fmaxf(yy2 - yy1, 0.0f);
      float inter = iw * ih;
      float iou = inter / (((ra + car[jj]) - inter) + 1e-9f);
      if (iou > 0.6f) m |= (1ull << jj);
    }
  }
  mask[((size_t)b * NDET + i) * NW + w] = m;
}

__global__ __launch_bounds__(64) void k_scan(const u64* mask, const float* ssc,
                                             const int* sval, float* out) {
  int b = blockIdx.x;
  int lane = threadIdx.x;                   // 64 threads = 1 wave
  __shared__ u64 rem[NW];
  __shared__ int rowsbuf[64];
  __shared__ float sh_kth;
  __shared__ int sh_nd;
  for (int w = lane; w < NW; w += 64) {
    u64 m = 0ull;
    for (int bit = 0; bit < 64; ++bit) {
      int i = w * 64 + bit;
      if (i >= NDET || !sval[b * NDET + i]) m |= (1ull << bit);
    }
    rem[w] = m;                             // removed = ~valid (padding removed)
  }
  __syncthreads();
  for (int c = 0; c < NW; ++c) {
    u64 alive = ~rem[c];
    if (alive != 0ull) {
      int row = c * 64 + lane;
      u64 diag = (row < NDET) ? mask[((size_t)b * NDET + row) * NW + c] : 0ull;
      for (int bit = 0; bit < 64; ++bit) {   // greedy within chunk (uniform)
        if ((alive >> bit) & 1ull) {
          u64 dw = shfl64(diag, bit);
          alive &= ~dw;
        }
      }
      if (lane == 0) rem[c] = ~alive;
      int nr = __popcll(alive);
      if ((alive >> lane) & 1ull) {
        int pp = __popcll(alive & ((1ull << lane) - 1ull));
        rowsbuf[pp] = c * 64 + lane;
      }
      __syncthreads();
      for (int w2 = c + 1 + lane; w2 < NW; w2 += 64) {   // apply survivors forward
        u64 acc = rem[w2];
        for (int q = 0; q < nr; ++q)
          acc |= mask[((size_t)b * NDET + rowsbuf[q]) * NW + w2];
        rem[w2] = acc;
      }
    }
    __syncthreads();
  }
  if (lane == 0) {
    int nd = 0;
    for (int w = 0; w < NW; ++w) nd += __popcll(~rem[w]);
    float kth = 0.0f;
    if (nd > 100) {                          // kth = 100th kept score (desc order)
      int cum = 0;
      for (int w = 0; w < NW; ++w) {
        u64 kw = ~rem[w];
        int pc = __popcll(kw);
        if (cum + pc >= 100) {
          int need = 100 - cum;
          u64 mm = kw; int bp = 0;
          for (int t = 0; t < need; ++t) { bp = __ffsll(mm) - 1; mm &= mm - 1ull; }
          kth = ssc[b * NDET + w * 64 + bp];
          break;
        }
        cum += pc;
      }
    }
    sh_nd = nd; sh_kth = kth;
  }
  __syncthreads();
  int nd = sh_nd; float kth = sh_kth;
  for (int i = lane; i < NDET; i += 64) {
    bool kp = ((~rem[i >> 6] >> (i & 63)) & 1ull) != 0ull;
    float sc = ssc[b * NDET + i];
    bool kf = kp && (nd > 100 ? (sc >= kth) : true);
    out[SC_BASE + b * NDET + i] = kf ? sc : 0.0f;
    out[KEEP_BASE + b * NDET + i] = kf ? 1.0f : 0.0f;
  }
}

extern "C" void kernel_launch(void* const* d_in, const int* in_sizes, int n_in,
                              void* d_out, int out_size, void* d_ws, size_t ws_size,
                              hipStream_t stream) {
  (void)n_in; (void)out_size; (void)ws_size;
  Ptrs p;
  // setup_inputs() dict order is interleaved (loc0,cls0,box0,ctr0,loc1,...);
  // detect signature-grouped order defensively via in_sizes[1].
  bool interleaved = (in_sizes[1] == 204800);
  for (int l = 0; l < 5; ++l) {
    if (interleaved) {
      p.loc[l] = (const float*)d_in[4 * l + 0];
      p.cls[l] = (const float*)d_in[4 * l + 1];
      p.box[l] = (const float*)d_in[4 * l + 2];
      p.ctr[l] = (const float*)d_in[4 * l + 3];
    } else {
      p.loc[l] = (const float*)d_in[l];
      p.cls[l] = (const float*)d_in[5 + l];
      p.box[l] = (const float*)d_in[10 + l];
      p.ctr[l] = (const float*)d_in[15 + l];
    }
  }

  char* base = (char*)d_ws;
  size_t o = 0;
  auto carve = [&](size_t bytes) -> void* {
    void* r = base + o;
    o += (bytes + 511) & ~(size_t)511;
    return r;
  };
  u32* hist   = (u32*)carve((size_t)10 * 65536 * 4);   // 2.62 MB
  u32* cut    = (u32*)carve(64);
  u32* cnt    = (u32*)carve(64);
  u64* keyb   = (u64*)carve((size_t)TOTE * 8);         // 2.18 MB
  u64* cand   = (u64*)carve((size_t)10 * CAND_CAP * 8);// 0.66 MB
  float* px1  = (float*)carve((size_t)2 * NDET * 4);
  float* py1  = (float*)carve((size_t)2 * NDET * 4);
  float* px2  = (float*)carve((size_t)2 * NDET * 4);
  float* py2  = (float*)carve((size_t)2 * NDET * 4);
  float* psc  = (float*)carve((size_t)2 * NDET * 4);
  int*   plab = (int*)carve((size_t)2 * NDET * 4);
  int*   pval = (int*)carve((size_t)2 * NDET * 4);
  float* ssc  = (float*)carve((size_t)2 * NDET * 4);
  int*   sval = (int*)carve((size_t)2 * NDET * 4);
  float* ox1  = (float*)carve((size_t)2 * NDET * 4);
  float* oy1  = (float*)carve((size_t)2 * NDET * 4);
  float* ox2  = (float*)carve((size_t)2 * NDET * 4);
  float* oy2  = (float*)carve((size_t)2 * NDET * 4);
  float* oarea= (float*)carve((size_t)2 * NDET * 4);
  u64* mask   = (u64*)carve((size_t)2 * NDET * NW * 8);// 4.98 MB  (total ~11 MB)
  float* out  = (float*)d_out;

  hipLaunchKernelGGL(k_zero,       dim3(2560), dim3(256), 0, stream, hist, cnt);
  hipLaunchKernelGGL(k_keys_hist,  dim3(1067), dim3(256), 0, stream, p, keyb, hist);
  hipLaunchKernelGGL(k_select,     dim3(10),   dim3(256), 0, stream, hist, cut);
  hipLaunchKernelGGL(k_gather,     dim3(1067), dim3(256), 0, stream, keyb, cut, cnt, cand);
  hipLaunchKernelGGL(k_sortdecode, dim3(10),   dim3(1024), 65536, stream,
                     p, cand, cnt, px1, py1, px2, py2, psc, plab, pval);
  hipLaunchKernelGGL(k_globalsort, dim3(2),    dim3(1024), 65536, stream,
                     px1, py1, px2, py2, psc, plab, pval, out, ssc, sval,
                     ox1, oy1, ox2, oy2, oarea);
  hipLaunchKernelGGL(k_mask,       dim3(NW, NW, 2), dim3(64), 0, stream,
                     ox1, oy1, ox2, oy2, oarea, mask);
  hipLaunchKernelGGL(k_scan,       dim3(2),    dim3(64), 0, stream, mask, ssc, sval, out);
}

// Round 10
// 685.140 us; speedup vs baseline: 2.9126x; 2.9126x over previous
//
#include <hip/hip_runtime.h>
#include <math.h>

typedef unsigned long long u64;
typedef unsigned int u32;

#define TOTE      273024      // 2 * 136512 score elements
#define BTOT      136512
#define NDET      4448        // 1000*4 + 448
#define NW        70          // ceil(4448/64)
#define SC_BASE   35584       // 2*4448*4
#define LAB_BASE  44480
#define KEEP_BASE 53376
#define CAND_CAP  8192

struct Ptrs {
  const float* loc[5];
  const float* cls[5];
  const float* box[5];
  const float* ctr[5];
};

__constant__ int c_HW[5]  = {12800, 3200, 800, 208, 56};
__constant__ int c_K[5]   = {1000, 1000, 1000, 1000, 448};
__constant__ int c_OFF[5] = {0, 1000, 2000, 3000, 4000};

// XLA LogisticExpander: logistic(x) = 1 / (1 + exp(-x)).
// expf() == __ocml_exp_f32 on ROCm -> bit-identical to a jax-rocm reference.
// VERIFIED round 3: absmax == 0.0.
__device__ __forceinline__ float ref_sigmoid(float x) {
#pragma clang fp contract(off)
  float e = expf(-x);
  return 1.0f / (1.0f + e);
}

__device__ __forceinline__ u32 ordf(float v) {
  u32 b = __float_as_uint(v);
  return (b & 0x80000000u) ? ~b : (b | 0x80000000u);
}
__device__ __forceinline__ float unordf(u32 o) {
  u32 b = (o & 0x80000000u) ? (o ^ 0x80000000u) : ~o;
  return __uint_as_float(b);
}

__device__ __forceinline__ u64 shfl64(u64 v, int src) {
  int lo = __shfl((int)(u32)(v & 0xFFFFFFFFull), src, 64);
  int hi = __shfl((int)(u32)(v >> 32), src, 64);
  return ((u64)(u32)hi << 32) | (u32)lo;
}

// element id -> (segment = b*5+l, local flat index f within segment)
__device__ __forceinline__ int seg_decompose(int e, int& f) {
  int b = 0;
  if (e >= BTOT) { b = 1; e -= BTOT; }
  int l, base;
  if      (e < 102400) { l = 0; base = 0; }
  else if (e < 128000) { l = 1; base = 102400; }
  else if (e < 134400) { l = 2; base = 128000; }
  else if (e < 136064) { l = 3; base = 134400; }
  else                 { l = 4; base = 136064; }
  f = e - base;
  return b * 5 + l;
}

__global__ __launch_bounds__(256) void k_zero(u32* hist, u32* cnt,
                                              u64* rowAnyA, u32* rowAnyB) {
  int i = blockIdx.x * 256 + threadIdx.x;
  if (i < 10 * 65536) hist[i] = 0u;
  if (i < 16) cnt[i] = 0u;
  if (i < 2 * NDET) { rowAnyA[i] = 0ull; rowAnyB[i] = 0u; }
}

__global__ __launch_bounds__(256) void k_keys_hist(Ptrs p, u64* keyb, u32* hist) {
#pragma clang fp contract(off)
  int e = blockIdx.x * 256 + threadIdx.x;
  if (e >= TOTE) return;
  int f; int s = seg_decompose(e, f);
  int b = s / 5, l = s % 5;
  int hw = f >> 3, c = f & 7;
  int HW = c_HW[l];
  float cp = ref_sigmoid(p.cls[l][(size_t)(b * 8 + c) * HW + hw]);
  float flatv = -1.0f;
  if (cp > 0.05f) {
    float tp = ref_sigmoid(p.ctr[l][(size_t)b * HW + hw]);
    flatv = cp * tp;   // score = cls_p * ctr_p
  }
  u32 o = ordf(flatv);
  keyb[e] = ((u64)o << 32) | (0xFFFFFFFFu - (u32)f);  // desc value, asc idx
  atomicAdd(&hist[(s << 16) + (o >> 16)], 1u);
}

__global__ __launch_bounds__(256) void k_select(const u32* hist, u32* cut) {
  __shared__ u32 cs[256];
  int s = blockIdx.x, tid = threadIdx.x;
  const u32* h = hist + (s << 16);
  u32 sum = 0;
  for (int i = 0; i < 256; ++i) sum += h[tid * 256 + i];
  cs[tid] = sum;
  __syncthreads();
  if (tid == 0) {
    u32 k = (u32)c_K[s % 5];
    u32 cum = 0; int bstar = 0;
    for (int ch = 255; ch >= 0; --ch) {
      if (cum + cs[ch] >= k) {
        for (int bb = 255; bb >= 0; --bb) {
          u32 c2 = h[ch * 256 + bb];
          if (cum + c2 >= k) { bstar = ch * 256 + bb; break; }
          cum += c2;
        }
        break;
      }
      cum += cs[ch];
    }
    cut[s] = (u32)bstar;
  }
}

__global__ __launch_bounds__(256) void k_gather(const u64* keyb, const u32* cut,
                                                u32* cnt, u64* cand) {
  int e = blockIdx.x * 256 + threadIdx.x;
  if (e >= TOTE) return;
  int f; int s = seg_decompose(e, f);
  u64 key = keyb[e];
  u32 bin = (u32)(key >> 48);
  if (bin >= cut[s]) {
    u32 pos = atomicAdd(&cnt[s], 1u);
    if (pos < CAND_CAP) cand[((size_t)s << 13) + pos] = key;
  }
}

__device__ __forceinline__ void bitonic8192_desc(u64* sb, int tid, int nthr) {
  for (u32 k = 2; k <= 8192; k <<= 1) {
    for (u32 j = k >> 1; j > 0; j >>= 1) {
      __syncthreads();
      for (u32 i = (u32)tid; i < 8192; i += (u32)nthr) {
        u32 l = i ^ j;
        if (l > i) {
          u64 a = sb[i], b = sb[l];
          bool up = ((i & k) != 0);           // inverted -> final descending
          if (up ? (a > b) : (a < b)) { sb[i] = b; sb[l] = a; }
        }
      }
    }
  }
  __syncthreads();
}

extern __shared__ u64 sbuf[];

__global__ __launch_bounds__(1024) void k_sortdecode(Ptrs p, const u64* cand, const u32* cnt,
                             float* px1, float* py1, float* px2, float* py2,
                             float* psc, int* plab, int* pval) {
#pragma clang fp contract(off)
  int s = blockIdx.x, tid = threadIdx.x;
  int b = s / 5, l = s % 5;
  int n = (int)cnt[s]; if (n > CAND_CAP) n = CAND_CAP;
  for (int i = tid; i < 8192; i += 1024)
    sbuf[i] = (i < n) ? cand[((size_t)s << 13) + i] : 0ull;
  __syncthreads();
  bitonic8192_desc(sbuf, tid, 1024);
  int k = c_K[l], off = c_OFF[l], HW = c_HW[l];
  for (int r = tid; r < k; r += 1024) {
    int pos = b * NDET + off + r;
    if (r < n) {
      u64 key = sbuf[r];
      float val = unordf((u32)(key >> 32));
      u32 f = 0xFFFFFFFFu - (u32)(key & 0xFFFFFFFFull);
      int hw = (int)(f >> 3), c = (int)(f & 7);
      float x = p.loc[l][hw * 2 + 0], y = p.loc[l][hw * 2 + 1];
      float b0 = p.box[l][(size_t)(b * 4 + 0) * HW + hw];
      float b1 = p.box[l][(size_t)(b * 4 + 1) * HW + hw];
      float b2 = p.box[l][(size_t)(b * 4 + 2) * HW + hw];
      float b3 = p.box[l][(size_t)(b * 4 + 3) * HW + hw];
      float d0 = x - b0, d1 = y - b1, d2 = x + b2, d3 = y + b3;
      float x1 = fminf(fmaxf(d0, 0.0f), 1023.0f);   // clip to [0, W-1]
      float y1 = fminf(fmaxf(d1, 0.0f), 799.0f);    // clip to [0, H-1]
      float x2 = fminf(fmaxf(d2, 0.0f), 1023.0f);
      float y2 = fminf(fmaxf(d3, 0.0f), 799.0f);
      int valid = (val > 0.0f) ? 1 : 0;
      if (!((x2 - x1 + 1.0f) >= 0.0f) || !((y2 - y1 + 1.0f) >= 0.0f)) valid = 0;
      float sc = valid ? sqrtf(val) : 0.0f;
      px1[pos] = x1; py1[pos] = y1; px2[pos] = x2; py2[pos] = y2;
      psc[pos] = sc; plab[pos] = c + 1; pval[pos] = valid;
    } else {
      px1[pos] = 0.f; py1[pos] = 0.f; px2[pos] = 0.f; py2[pos] = 0.f;
      psc[pos] = 0.f; plab[pos] = 1; pval[pos] = 0;
    }
  }
}

__global__ __launch_bounds__(1024) void k_globalsort(const float* px1, const float* py1,
                             const float* px2, const float* py2,
                             const float* psc, const int* plab, const int* pval,
                             float* out, float* ssc, int* sval,
                             float* ox1, float* oy1, float* ox2, float* oy2, float* oarea) {
#pragma clang fp contract(off)
  int b = blockIdx.x, tid = threadIdx.x;
  for (int i = tid; i < 8192; i += 1024) {
    u64 key = 0ull;
    if (i < NDET) {
      int g = b * NDET + i;
      float v = pval[g] ? psc[g] : -1.0f;   // argsort(-where(valid, sc, -1)), stable
      key = ((u64)ordf(v) << 32) | (0xFFFFFFFFu - (u32)i);
    }
    sbuf[i] = key;
  }
  __syncthreads();
  bitonic8192_desc(sbuf, tid, 1024);
  for (int r = tid; r < NDET; r += 1024) {
    u64 key = sbuf[r];
    int g = (int)(0xFFFFFFFFu - (u32)(key & 0xFFFFFFFFull));
    int src = b * NDET + g, dst = b * NDET + r;
    float x1 = px1[src], y1 = py1[src], x2 = px2[src], y2 = py2[src];
    out[(size_t)dst * 4 + 0] = x1;
    out[(size_t)dst * 4 + 1] = y1;
    out[(size_t)dst * 4 + 2] = x2;
    out[(size_t)dst * 4 + 3] = y2;
    float labf = (float)plab[src];
    out[LAB_BASE + dst] = labf;
    ssc[dst] = psc[src];
    sval[dst] = pval[src];
    float a1 = x1 + labf * 4096.0f;   // bo = boxes + label*CLASS_OFFSET (no fma!)
    float c1 = y1 + labf * 4096.0f;
    float a2 = x2 + labf * 4096.0f;
    float c2 = y2 + labf * 4096.0f;
    ox1[dst] = a1; oy1[dst] = c1; ox2[dst] = a2; oy2[dst] = c2;
    oarea[dst] = (a2 - a1) * (c2 - c1);
  }
}

__global__ __launch_bounds__(64) void k_mask(const float* ox1, const float* oy1,
                       const float* ox2, const float* oy2,
                       const float* oarea, u64* mask,
                       u64* rowAnyA, u32* rowAnyB) {
#pragma clang fp contract(off)
  int w = blockIdx.x, ti = blockIdx.y, b = blockIdx.z;
  if (w < ti) return;                       // j <= i tiles never read
  int lane = threadIdx.x;
  __shared__ float cx1[64], cy1[64], cx2[64], cy2[64], car[64];
  int j0 = w * 64;
  int j = j0 + lane;
  if (j < NDET) {
    int g = b * NDET + j;
    cx1[lane] = ox1[g]; cy1[lane] = oy1[g];
    cx2[lane] = ox2[g]; cy2[lane] = oy2[g];
    car[lane] = oarea[g];
  }
  __syncthreads();
  int i = ti * 64 + lane;
  if (i >= NDET) return;
  int g = b * NDET + i;
  float rx1 = ox1[g], ry1 = oy1[g], rx2 = ox2[g], ry2 = oy2[g], ra = oarea[g];
  u64 m = 0ull;
  int jmax = NDET - j0; if (jmax > 64) jmax = 64;
  for (int jj = 0; jj < jmax; ++jj) {
    int jg = j0 + jj;
    if (jg > i) {
      float xx1 = fmaxf(rx1, cx1[jj]);
      float yy1 = fmaxf(ry1, cy1[jj]);
      float xx2 = fminf(rx2, cx2[jj]);
      float yy2 = fminf(ry2, cy2[jj]);
      float iw = fmaxf(xx2 - xx1, 0.0f);
      float ih = fmaxf(yy2 - yy1, 0.0f);
      float inter = iw * ih;
      float iou = inter / (((ra + car[jj]) - inter) + 1e-9f);
      if (iou > 0.6f) m |= (1ull << jj);
    }
  }
  mask[((size_t)b * NDET + i) * NW + w] = m;
  if (m) {   // sparse summary: bit w of row i's nonzero-word bitmap
    if (w < 64) atomicOr(&rowAnyA[b * NDET + i], 1ull << w);
    else        atomicOr(&rowAnyB[b * NDET + i], 1u << (w - 64));
  }
}

// Sparsity-directed greedy scan: per chunk, the diagonal resolve runs only
// when a live row actually has a nonzero diagonal word (rowAny bit c), and
// forward-apply walks only each surviving row's nonzero words. Worst case
// degrades to the dense algorithm; random-box data is >99% zeros.
__global__ __launch_bounds__(64) void k_scan(const u64* mask,
                                             const u64* rowAnyA, const u32* rowAnyB,
                                             const float* ssc, const int* sval,
                                             float* out) {
  int b = blockIdx.x;
  int lane = threadIdx.x;                   // 64 threads = 1 wave
  __shared__ float sh_kth;
  __shared__ int sh_nd;
  u64* rowA = sbuf;                                   // NDET u64  (35584 B)
  unsigned char* rowB = (unsigned char*)(sbuf + NDET);// NDET u8   (4448 B)
  u32* remLo = (u32*)(rowB + NDET);                   // NW u32
  u32* remHi = remLo + NW;                            // NW u32

  for (int i = lane; i < NDET; i += 64) {
    rowA[i] = rowAnyA[b * NDET + i];
    rowB[i] = (unsigned char)rowAnyB[b * NDET + i];
  }
  for (int i0 = 0; i0 < NW * 64; i0 += 64) {          // rem init via ballot
    int i = i0 + lane;
    u64 bb = __ballot((i < NDET) && (sval[b * NDET + i] != 0));
    if (lane == 0) {
      u64 rm = ~bb;                                   // removed = ~valid
      remLo[i0 >> 6] = (u32)rm; remHi[i0 >> 6] = (u32)(rm >> 32);
    }
  }
  __syncthreads();

  for (int c = 0; c < NW; ++c) {
    u64 rem = ((u64)remHi[c] << 32) | remLo[c];
    u64 alive = ~rem;
    if (alive == 0ull) continue;                      // uniform skip
    int row = c * 64 + lane;
    bool inr = (row < NDET);
    u64 rA = inr ? rowA[row] : 0ull;
    u32 rB = inr ? (u32)rowB[row] : 0u;
    bool hasDiag = (c < 64) ? (((rA >> c) & 1ull) != 0ull)
                            : (((rB >> (c - 64)) & 1u) != 0u);
    u64 anyD = __ballot(hasDiag);
    if (anyD & alive) {                               // intra-chunk suppression exists
      u64 diag = hasDiag ? mask[((size_t)b * NDET + row) * NW + c] : 0ull;
      u64 a2 = alive;
      u64 it = anyD;                                  // only bits that can suppress
      while (it) {
        int bit = __ffsll(it) - 1; it &= it - 1ull;
        if ((a2 >> bit) & 1ull) {                     // still kept at its turn
          u64 dw = shfl64(diag, bit);
          a2 &= ~dw;
        }
      }
      if (lane == 0) {
        u64 nr2 = ~a2;
        remLo[c] = (u32)nr2; remHi[c] = (u32)(nr2 >> 32);
      }
      alive = a2;
    }
    // forward apply: each surviving lane walks its own row's nonzero words > c
    if (inr && ((alive >> lane) & 1ull)) {
      u64 fa; u32 fb;
      if (c < 64) { fa = rA & ~((2ull << c) - 1ull); fb = rB; }
      else        { fa = 0ull; fb = rB & ~((2u << (c - 64)) - 1u); }
      while (fa) {
        int w2 = __ffsll(fa) - 1; fa &= fa - 1ull;
        u64 m = mask[((size_t)b * NDET + row) * NW + w2];
        u32 lo = (u32)m, hi = (u32)(m >> 32);
        if (lo) atomicOr(&remLo[w2], lo);
        if (hi) atomicOr(&remHi[w2], hi);
      }
      while (fb) {
        int w2 = 64 + __ffs(fb) - 1; fb &= fb - 1u;
        u64 m = mask[((size_t)b * NDET + row) * NW + w2];
        u32 lo = (u32)m, hi = (u32)(m >> 32);
        if (lo) atomicOr(&remLo[w2], lo);
        if (hi) atomicOr(&remHi[w2], hi);
      }
    }
    __syncthreads();                                  // publish atomics to next chunk
  }

  if (lane == 0) {
    int nd = 0;
    for (int w = 0; w < NW; ++w)
      nd += __popcll(~(((u64)remHi[w] << 32) | remLo[w]));
    float kth = 0.0f;
    if (nd > 100) {                          // kth = 100th kept score (desc order)
      int cum = 0;
      for (int w = 0; w < NW; ++w) {
        u64 kw = ~(((u64)remHi[w] << 32) | remLo[w]);
        int pc = __popcll(kw);
        if (cum + pc >= 100) {
          int need = 100 - cum;
          u64 mm = kw; int bp = 0;
          for (int t = 0; t < need; ++t) { bp = __ffsll(mm) - 1; mm &= mm - 1ull; }
          kth = ssc[b * NDET + w * 64 + bp];
          break;
        }
        cum += pc;
      }
    }
    sh_nd = nd; sh_kth = kth;
  }
  __syncthreads();
  int nd = sh_nd; float kth = sh_kth;
  for (int i = lane; i < NDET; i += 64) {
    bool kp = ((~(((u64)remHi[i >> 6] << 32) | remLo[i >> 6]) >> (i & 63)) & 1ull) != 0ull;
    float sc = ssc[b * NDET + i];
    bool kf = kp && (nd > 100 ? (sc >= kth) : true);
    out[SC_BASE + b * NDET + i] = kf ? sc : 0.0f;
    out[KEEP_BASE + b * NDET + i] = kf ? 1.0f : 0.0f;
  }
}

extern "C" void kernel_launch(void* const* d_in, const int* in_sizes, int n_in,
                              void* d_out, int out_size, void* d_ws, size_t ws_size,
                              hipStream_t stream) {
  (void)n_in; (void)out_size; (void)ws_size;
  Ptrs p;
  // setup_inputs() dict order is interleaved (loc0,cls0,box0,ctr0,loc1,...);
  // detect signature-grouped order defensively via in_sizes[1].
  bool interleaved = (in_sizes[1] == 204800);
  for (int l = 0; l < 5; ++l) {
    if (interleaved) {
      p.loc[l] = (const float*)d_in[4 * l + 0];
      p.cls[l] = (const float*)d_in[4 * l + 1];
      p.box[l] = (const float*)d_in[4 * l + 2];
      p.ctr[l] = (const float*)d_in[4 * l + 3];
    } else {
      p.loc[l] = (const float*)d_in[l];
      p.cls[l] = (const float*)d_in[5 + l];
      p.box[l] = (const float*)d_in[10 + l];
      p.ctr[l] = (const float*)d_in[15 + l];
    }
  }

  char* base = (char*)d_ws;
  size_t o = 0;
  auto carve = [&](size_t bytes) -> void* {
    void* r = base + o;
    o += (bytes + 511) & ~(size_t)511;
    return r;
  };
  u32* hist   = (u32*)carve((size_t)10 * 65536 * 4);   // 2.62 MB
  u32* cut    = (u32*)carve(64);
  u32* cnt    = (u32*)carve(64);
  u64* keyb   = (u64*)carve((size_t)TOTE * 8);         // 2.18 MB
  u64* cand   = (u64*)carve((size_t)10 * CAND_CAP * 8);// 0.66 MB
  float* px1  = (float*)carve((size_t)2 * NDET * 4);
  float* py1  = (float*)carve((size_t)2 * NDET * 4);
  float* px2  = (float*)carve((size_t)2 * NDET * 4);
  float* py2  = (float*)carve((size_t)2 * NDET * 4);
  float* psc  = (float*)carve((size_t)2 * NDET * 4);
  int*   plab = (int*)carve((size_t)2 * NDET * 4);
  int*   pval = (int*)carve((size_t)2 * NDET * 4);
  float* ssc  = (float*)carve((size_t)2 * NDET * 4);
  int*   sval = (int*)carve((size_t)2 * NDET * 4);
  float* ox1  = (float*)carve((size_t)2 * NDET * 4);
  float* oy1  = (float*)carve((size_t)2 * NDET * 4);
  float* ox2  = (float*)carve((size_t)2 * NDET * 4);
  float* oy2  = (float*)carve((size_t)2 * NDET * 4);
  float* oarea= (float*)carve((size_t)2 * NDET * 4);
  u64* mask   = (u64*)carve((size_t)2 * NDET * NW * 8);// 4.98 MB
  u64* rowAnyA= (u64*)carve((size_t)2 * NDET * 8);     // 71 KB
  u32* rowAnyB= (u32*)carve((size_t)2 * NDET * 4);     // 36 KB (total ~11.1 MB)
  float* out  = (float*)d_out;

  // k_scan dynamic LDS: rowA (NDET u64) + rowB (NDET u8) + remLo/remHi (NW u32 each)
  const size_t scan_lds = (size_t)NDET * 8 + (size_t)NDET + (size_t)NW * 4 * 2 + 64;

  hipLaunchKernelGGL(k_zero,       dim3(2560), dim3(256), 0, stream,
                     hist, cnt, rowAnyA, rowAnyB);
  hipLaunchKernelGGL(k_keys_hist,  dim3(1067), dim3(256), 0, stream, p, keyb, hist);
  hipLaunchKernelGGL(k_select,     dim3(10),   dim3(256), 0, stream, hist, cut);
  hipLaunchKernelGGL(k_gather,     dim3(1067), dim3(256), 0, stream, keyb, cut, cnt, cand);
  hipLaunchKernelGGL(k_sortdecode, dim3(10),   dim3(1024), 65536, stream,
                     p, cand, cnt, px1, py1, px2, py2, psc, plab, pval);
  hipLaunchKernelGGL(k_globalsort, dim3(2),    dim3(1024), 65536, stream,
                     px1, py1, px2, py2, psc, plab, pval, out, ssc, sval,
                     ox1, oy1, ox2, oy2, oarea);
  hipLaunchKernelGGL(k_mask,       dim3(NW, NW, 2), dim3(64), 0, stream,
                     ox1, oy1, ox2, oy2, oarea, mask, rowAnyA, rowAnyB);
  hipLaunchKernelGGL(k_scan,       dim3(2),    dim3(64), scan_lds, stream,
                     mask, rowAnyA, rowAnyB, ssc, sval, out);
}

// Round 12
// 540.691 us; speedup vs baseline: 3.6908x; 1.2672x over previous
//
#include <hip/hip_runtime.h>
#include <math.h>

typedef unsigned long long u64;
typedef unsigned int u32;

#define TOTE      273024      // 2 * 136512 score elements
#define BTOT      136512
#define NDET      4448        // 1000*4 + 448
#define NW        70          // ceil(4448/64)
#define SC_BASE   35584       // 2*4448*4
#define LAB_BASE  44480
#define KEEP_BASE 53376
#define CAND_CAP  8192

struct Ptrs {
  const float* loc[5];
  const float* cls[5];
  const float* box[5];
  const float* ctr[5];
};

__constant__ int c_HW[5]  = {12800, 3200, 800, 208, 56};
__constant__ int c_K[5]   = {1000, 1000, 1000, 1000, 448};
__constant__ int c_OFF[5] = {0, 1000, 2000, 3000, 4000};

// XLA LogisticExpander: logistic(x) = 1 / (1 + exp(-x)).
// expf() == __ocml_exp_f32 on ROCm -> bit-identical to the jax-rocm reference.
// VERIFIED rounds 3 & 10: absmax == 0.0.
__device__ __forceinline__ float ref_sigmoid(float x) {
#pragma clang fp contract(off)
  float e = expf(-x);
  return 1.0f / (1.0f + e);
}

__device__ __forceinline__ u32 ordf(float v) {
  u32 b = __float_as_uint(v);
  return (b & 0x80000000u) ? ~b : (b | 0x80000000u);
}
__device__ __forceinline__ float unordf(u32 o) {
  u32 b = (o & 0x80000000u) ? (o ^ 0x80000000u) : ~o;
  return __uint_as_float(b);
}

__device__ __forceinline__ u64 shfl64(u64 v, int src) {
  int lo = __shfl((int)(u32)(v & 0xFFFFFFFFull), src, 64);
  int hi = __shfl((int)(u32)(v >> 32), src, 64);
  return ((u64)(u32)hi << 32) | (u32)lo;
}

// element id -> (segment = b*5+l, local flat index f within segment)
__device__ __forceinline__ int seg_decompose(int e, int& f) {
  int b = 0;
  if (e >= BTOT) { b = 1; e -= BTOT; }
  int l, base;
  if      (e < 102400) { l = 0; base = 0; }
  else if (e < 128000) { l = 1; base = 102400; }
  else if (e < 134400) { l = 2; base = 128000; }
  else if (e < 136064) { l = 3; base = 134400; }
  else                 { l = 4; base = 136064; }
  f = e - base;
  return b * 5 + l;
}

__global__ __launch_bounds__(256) void k_zero(u32* hist, u32* cnt,
                                              u64* rowAnyA, u32* rowAnyB) {
  int i = blockIdx.x * 256 + threadIdx.x;
  if (i < 10 * 65536) hist[i] = 0u;
  if (i < 16) cnt[i] = 0u;
  if (i < 2 * NDET) { rowAnyA[i] = 0ull; rowAnyB[i] = 0u; }
}

__global__ __launch_bounds__(256) void k_keys_hist(Ptrs p, u64* keyb, u32* hist) {
#pragma clang fp contract(off)
  int e = blockIdx.x * 256 + threadIdx.x;
  if (e >= TOTE) return;
  int f; int s = seg_decompose(e, f);
  int b = s / 5, l = s % 5;
  int hw = f >> 3, c = f & 7;
  int HW = c_HW[l];
  float cp = ref_sigmoid(p.cls[l][(size_t)(b * 8 + c) * HW + hw]);
  float flatv = -1.0f;
  if (cp > 0.05f) {
    float tp = ref_sigmoid(p.ctr[l][(size_t)b * HW + hw]);
    flatv = cp * tp;   // score = cls_p * ctr_p
  }
  u32 o = ordf(flatv);
  keyb[e] = ((u64)o << 32) | (0xFFFFFFFFu - (u32)f);  // desc value, asc idx
  atomicAdd(&hist[(s << 16) + (o >> 16)], 1u);
}

// R10: uint4 vectorized per-thread sums (latency-bound stride loads /4),
// and the chosen chunk's bins staged to LDS cooperatively before the serial
// tid0 scan (was: 256 serially-dependent global loads).
__global__ __launch_bounds__(256) void k_select(const u32* hist, u32* cut) {
  __shared__ u32 cs[256];
  __shared__ u32 binbuf[256];
  __shared__ int sh_ch;
  __shared__ u32 sh_cum;
  int s = blockIdx.x, tid = threadIdx.x;
  const u32* h = hist + (s << 16);
  const uint4* h4 = (const uint4*)(h + tid * 256);
  u32 sum = 0;
  for (int i = 0; i < 64; ++i) {
    uint4 v = h4[i];
    sum += v.x + v.y + v.z + v.w;
  }
  cs[tid] = sum;
  __syncthreads();
  if (tid == 0) {
    u32 k = (u32)c_K[s % 5];
    u32 cum = 0; int ch = 0;
    for (int c2 = 255; c2 >= 0; --c2) {
      if (cum + cs[c2] >= k) { ch = c2; break; }
      cum += cs[c2];
    }
    sh_ch = ch; sh_cum = cum;
  }
  __syncthreads();
  binbuf[tid] = h[sh_ch * 256 + tid];   // coalesced stage of chosen chunk
  __syncthreads();
  if (tid == 0) {
    u32 k = (u32)c_K[s % 5];
    u32 cum = sh_cum; int ch = sh_ch; int bstar = ch * 256;
    for (int bb = 255; bb >= 0; --bb) {
      u32 c2 = binbuf[bb];
      if (cum + c2 >= k) { bstar = ch * 256 + bb; break; }
      cum += c2;
    }
    cut[s] = (u32)bstar;
  }
}

__global__ __launch_bounds__(256) void k_gather(const u64* keyb, const u32* cut,
                                                u32* cnt, u64* cand) {
  int e = blockIdx.x * 256 + threadIdx.x;
  if (e >= TOTE) return;
  int f; int s = seg_decompose(e, f);
  u64 key = keyb[e];
  u32 bin = (u32)(key >> 48);
  if (bin >= cut[s]) {
    u32 pos = atomicAdd(&cnt[s], 1u);
    if (pos < CAND_CAP) cand[((size_t)s << 13) + pos] = key;
  }
}

// Bitonic sort, descending, over m (power of 2) elements.
__device__ __forceinline__ void bitonic_desc(u64* sb, int tid, int nthr, u32 m) {
  for (u32 k = 2; k <= m; k <<= 1) {
    for (u32 j = k >> 1; j > 0; j >>= 1) {
      __syncthreads();
      for (u32 i = (u32)tid; i < m; i += (u32)nthr) {
        u32 l = i ^ j;
        if (l > i) {
          u64 a = sb[i], b = sb[l];
          bool up = ((i & k) != 0);           // inverted -> final descending
          if (up ? (a > b) : (a < b)) { sb[i] = b; sb[l] = a; }
        }
      }
    }
  }
  __syncthreads();
}

extern __shared__ u64 sbuf[];

__global__ __launch_bounds__(1024) void k_sortdecode(Ptrs p, const u64* cand, const u32* cnt,
                             float* px1, float* py1, float* px2, float* py2,
                             float* psc, int* plab, int* pval) {
#pragma clang fp contract(off)
  int s = blockIdx.x, tid = threadIdx.x;
  int b = s / 5, l = s % 5;
  int n = (int)cnt[s]; if (n > CAND_CAP) n = CAND_CAP;
  // R10: sort only next_pow2(n) slots (cutoff construction guarantees n >= k,
  // so the first k sorted entries are identical to the full-8192 sort; zero
  // pads sort last since every real key has nonzero value bits).
  u32 m = 64; while ((int)m < n) m <<= 1;
  for (int i = tid; i < (int)m; i += 1024)
    sbuf[i] = (i < n) ? cand[((size_t)s << 13) + i] : 0ull;
  __syncthreads();
  bitonic_desc(sbuf, tid, 1024, m);
  int k = c_K[l], off = c_OFF[l], HW = c_HW[l];
  for (int r = tid; r < k; r += 1024) {
    int pos = b * NDET + off + r;
    if (r < n) {
      u64 key = sbuf[r];
      float val = unordf((u32)(key >> 32));
      u32 f = 0xFFFFFFFFu - (u32)(key & 0xFFFFFFFFull);
      int hw = (int)(f >> 3), c = (int)(f & 7);
      float x = p.loc[l][hw * 2 + 0], y = p.loc[l][hw * 2 + 1];
      float b0 = p.box[l][(size_t)(b * 4 + 0) * HW + hw];
      float b1 = p.box[l][(size_t)(b * 4 + 1) * HW + hw];
      float b2 = p.box[l][(size_t)(b * 4 + 2) * HW + hw];
      float b3 = p.box[l][(size_t)(b * 4 + 3) * HW + hw];
      float d0 = x - b0, d1 = y - b1, d2 = x + b2, d3 = y + b3;
      float x1 = fminf(fmaxf(d0, 0.0f), 1023.0f);   // clip to [0, W-1]
      float y1 = fminf(fmaxf(d1, 0.0f), 799.0f);    // clip to [0, H-1]
      float x2 = fminf(fmaxf(d2, 0.0f), 1023.0f);
      float y2 = fminf(fmaxf(d3, 0.0f), 799.0f);
      int valid = (val > 0.0f) ? 1 : 0;
      if (!((x2 - x1 + 1.0f) >= 0.0f) || !((y2 - y1 + 1.0f) >= 0.0f)) valid = 0;
      float sc = valid ? sqrtf(val) : 0.0f;
      px1[pos] = x1; py1[pos] = y1; px2[pos] = x2; py2[pos] = y2;
      psc[pos] = sc; plab[pos] = c + 1; pval[pos] = valid;
    } else {
      px1[pos] = 0.f; py1[pos] = 0.f; px2[pos] = 0.f; py2[pos] = 0.f;
      psc[pos] = 0.f; plab[pos] = 1; pval[pos] = 0;
    }
  }
}

__global__ __launch_bounds__(1024) void k_globalsort(const float* px1, const float* py1,
                             const float* px2, const float* py2,
                             const float* psc, const int* plab, const int* pval,
                             float* out, float* ssc, int* sval,
                             float* ox1, float* oy1, float* ox2, float* oy2, float* oarea) {
#pragma clang fp contract(off)
  int b = blockIdx.x, tid = threadIdx.x;
  for (int i = tid; i < 8192; i += 1024) {
    u64 key = 0ull;
    if (i < NDET) {
      int g = b * NDET + i;
      float v = pval[g] ? psc[g] : -1.0f;   // argsort(-where(valid, sc, -1)), stable
      key = ((u64)ordf(v) << 32) | (0xFFFFFFFFu - (u32)i);
    }
    sbuf[i] = key;
  }
  __syncthreads();
  bitonic_desc(sbuf, tid, 1024, 8192);
  for (int r = tid; r < NDET; r += 1024) {
    u64 key = sbuf[r];
    int g = (int)(0xFFFFFFFFu - (u32)(key & 0xFFFFFFFFull));
    int src = b * NDET + g, dst = b * NDET + r;
    float x1 = px1[src], y1 = py1[src], x2 = px2[src], y2 = py2[src];
    out[(size_t)dst * 4 + 0] = x1;
    out[(size_t)dst * 4 + 1] = y1;
    out[(size_t)dst * 4 + 2] = x2;
    out[(size_t)dst * 4 + 3] = y2;
    float labf = (float)plab[src];
    out[LAB_BASE + dst] = labf;
    ssc[dst] = psc[src];
    sval[dst] = pval[src];
    float a1 = x1 + labf * 4096.0f;   // bo = boxes + label*CLASS_OFFSET (no fma!)
    float c1 = y1 + labf * 4096.0f;
    float a2 = x2 + labf * 4096.0f;
    float c2 = y2 + labf * 4096.0f;
    ox1[dst] = a1; oy1[dst] = c1; ox2[dst] = a2; oy2[dst] = c2;
    oarea[dst] = (a2 - a1) * (c2 - c1);
  }
}

__global__ __launch_bounds__(64) void k_mask(const float* ox1, const float* oy1,
                       const float* ox2, const float* oy2,
                       const float* oarea, u64* mask,
                       u64* rowAnyA, u32* rowAnyB) {
#pragma clang fp contract(off)
  int w = blockIdx.x, ti = blockIdx.y, b = blockIdx.z;
  if (w < ti) return;                       // j <= i tiles never read
  int lane = threadIdx.x;
  __shared__ float cx1[64], cy1[64], cx2[64], cy2[64], car[64];
  int j0 = w * 64;
  int j = j0 + lane;
  if (j < NDET) {
    int g = b * NDET + j;
    cx1[lane] = ox1[g]; cy1[lane] = oy1[g];
    cx2[lane] = ox2[g]; cy2[lane] = oy2[g];
    car[lane] = oarea[g];
  }
  __syncthreads();
  int i = ti * 64 + lane;
  if (i >= NDET) return;
  int g = b * NDET + i;
  float rx1 = ox1[g], ry1 = oy1[g], rx2 = ox2[g], ry2 = oy2[g], ra = oarea[g];
  u64 m = 0ull;
  int jmax = NDET - j0; if (jmax > 64) jmax = 64;
  for (int jj = 0; jj < jmax; ++jj) {
    int jg = j0 + jj;
    if (jg > i) {
      float xx1 = fmaxf(rx1, cx1[jj]);
      float yy1 = fmaxf(ry1, cy1[jj]);
      float xx2 = fminf(rx2, cx2[jj]);
      float yy2 = fminf(ry2, cy2[jj]);
      float iw = fmaxf(xx2 - xx1, 0.0f);
      float ih = fmaxf(yy2 - yy1, 0.0f);
      float inter = iw * ih;
      float iou = inter / (((ra + car[jj]) - inter) + 1e-9f);
      if (iou > 0.6f) m |= (1ull << jj);
    }
  }
  mask[((size_t)b * NDET + i) * NW + w] = m;
  if (m) {   // sparse summary: bit w of row i's nonzero-word bitmap
    if (w < 64) atomicOr(&rowAnyA[b * NDET + i], 1ull << w);
    else        atomicOr(&rowAnyB[b * NDET + i], 1u << (w - 64));
  }
}

// Sparsity-directed greedy scan. R10: 1024 threads — init/output loops get
// 16x TLP (they were the latency floor: ~140 serial global-load iterations);
// the inherently serial chunk loop runs on wave 0 only, other waves wait at
// the per-chunk barrier.
__global__ __launch_bounds__(1024) void k_scan(const u64* mask,
                                               const u64* rowAnyA, const u32* rowAnyB,
                                               const float* ssc, const int* sval,
                                               float* out) {
  int b = blockIdx.x;
  int tid = threadIdx.x;
  int lane = tid & 63;
  int wid = tid >> 6;                       // 16 waves
  __shared__ float sh_kth;
  __shared__ int sh_nd;
  u64* rowA = sbuf;                                   // NDET u64  (35584 B)
  unsigned char* rowB = (unsigned char*)(sbuf + NDET);// NDET u8   (4448 B)
  u32* remLo = (u32*)(rowB + NDET);                   // NW u32
  u32* remHi = remLo + NW;                            // NW u32

  for (int i = tid; i < NDET; i += 1024) {
    rowA[i] = rowAnyA[b * NDET + i];
    rowB[i] = (unsigned char)rowAnyB[b * NDET + i];
  }
  for (int w = wid; w < NW; w += 16) {                // rem init: one word per wave
    int i = w * 64 + lane;
    u64 bb = __ballot((i < NDET) && (sval[b * NDET + i] != 0));
    if (lane == 0) {
      u64 rm = ~bb;                                   // removed = ~valid
      remLo[w] = (u32)rm; remHi[w] = (u32)(rm >> 32);
    }
  }
  __syncthreads();

  for (int c = 0; c < NW; ++c) {
    u64 rem = ((u64)remHi[c] << 32) | remLo[c];
    u64 alive = ~rem;
    if (alive == 0ull) continue;                      // uniform skip (LDS value)
    if (tid < 64) {                                   // wave 0 does the serial work
      int row = c * 64 + lane;
      bool inr = (row < NDET);
      u64 rA = inr ? rowA[row] : 0ull;
      u32 rB = inr ? (u32)rowB[row] : 0u;
      bool hasDiag = (c < 64) ? (((rA >> c) & 1ull) != 0ull)
                              : (((rB >> (c - 64)) & 1u) != 0u);
      u64 anyD = __ballot(hasDiag);
      if (anyD & alive) {                             // intra-chunk suppression exists
        u64 diag = hasDiag ? mask[((size_t)b * NDET + row) * NW + c] : 0ull;
        u64 a2 = alive;
        u64 it = anyD;                                // only bits that can suppress
        while (it) {
          int bit = __ffsll(it) - 1; it &= it - 1ull;
          if ((a2 >> bit) & 1ull) {                   // still kept at its turn
            u64 dw = shfl64(diag, bit);
            a2 &= ~dw;
          }
        }
        if (lane == 0) {
          u64 nr2 = ~a2;
          remLo[c] = (u32)nr2; remHi[c] = (u32)(nr2 >> 32);
        }
        alive = a2;
      }
      // forward apply: each surviving lane walks its own row's nonzero words > c
      if (inr && ((alive >> lane) & 1ull)) {
        u64 fa; u32 fb;
        if (c < 64) { fa = rA & ~((2ull << c) - 1ull); fb = rB; }
        else        { fa = 0ull; fb = rB & ~((2u << (c - 64)) - 1u); }
        while (fa) {
          int w2 = __ffsll(fa) - 1; fa &= fa - 1ull;
          u64 m = mask[((size_t)b * NDET + row) * NW + w2];
          u32 lo = (u32)m, hi = (u32)(m >> 32);
          if (lo) atomicOr(&remLo[w2], lo);
          if (hi) atomicOr(&remHi[w2], hi);
        }
        while (fb) {
          int w2 = 64 + __ffs(fb) - 1; fb &= fb - 1u;
          u64 m = mask[((size_t)b * NDET + row) * NW + w2];
          u32 lo = (u32)m, hi = (u32)(m >> 32);
          if (lo) atomicOr(&remLo[w2], lo);
          if (hi) atomicOr(&remHi[w2], hi);
        }
      }
    }
    __syncthreads();                                  // publish to next chunk
  }

  if (tid == 0) {
    int nd = 0;
    for (int w = 0; w < NW; ++w)
      nd += __popcll(~(((u64)remHi[w] << 32) | remLo[w]));
    float kth = 0.0f;
    if (nd > 100) {                          // kth = 100th kept score (desc order)
      int cum = 0;
      for (int w = 0; w < NW; ++w) {
        u64 kw = ~(((u64)remHi[w] << 32) | remLo[w]);
        int pc = __popcll(kw);
        if (cum + pc >= 100) {
          int need = 100 - cum;
          u64 mm = kw; int bp = 0;
          for (int t = 0; t < need; ++t) { bp = __ffsll(mm) - 1; mm &= mm - 1ull; }
          kth = ssc[b * NDET + w * 64 + bp];
          break;
        }
        cum += pc;
      }
    }
    sh_nd = nd; sh_kth = kth;
  }
  __syncthreads();
  int nd = sh_nd; float kth = sh_kth;
  for (int i = tid; i < NDET; i += 1024) {
    bool kp = ((~(((u64)remHi[i >> 6] << 32) | remLo[i >> 6]) >> (i & 63)) & 1ull) != 0ull;
    float sc = ssc[b * NDET + i];
    bool kf = kp && (nd > 100 ? (sc >= kth) : true);
    out[SC_BASE + b * NDET + i] = kf ? sc : 0.0f;
    out[KEEP_BASE + b * NDET + i] = kf ? 1.0f : 0.0f;
  }
}

extern "C" void kernel_launch(void* const* d_in, const int* in_sizes, int n_in,
                              void* d_out, int out_size, void* d_ws, size_t ws_size,
                              hipStream_t stream) {
  (void)n_in; (void)out_size; (void)ws_size;
  Ptrs p;
  // setup_inputs() dict order is interleaved (loc0,cls0,box0,ctr0,loc1,...);
  // detect signature-grouped order defensively via in_sizes[1].
  bool interleaved = (in_sizes[1] == 204800);
  for (int l = 0; l < 5; ++l) {
    if (interleaved) {
      p.loc[l] = (const float*)d_in[4 * l + 0];
      p.cls[l] = (const float*)d_in[4 * l + 1];
      p.box[l] = (const float*)d_in[4 * l + 2];
      p.ctr[l] = (const float*)d_in[4 * l + 3];
    } else {
      p.loc[l] = (const float*)d_in[l];
      p.cls[l] = (const float*)d_in[5 + l];
      p.box[l] = (const float*)d_in[10 + l];
      p.ctr[l] = (const float*)d_in[15 + l];
    }
  }

  char* base = (char*)d_ws;
  size_t o = 0;
  auto carve = [&](size_t bytes) -> void* {
    void* r = base + o;
    o += (bytes + 511) & ~(size_t)511;
    return r;
  };
  u32* hist   = (u32*)carve((size_t)10 * 65536 * 4);   // 2.62 MB
  u32* cut    = (u32*)carve(64);
  u32* cnt    = (u32*)carve(64);
  u64* keyb   = (u64*)carve((size_t)TOTE * 8);         // 2.18 MB
  u64* cand   = (u64*)carve((size_t)10 * CAND_CAP * 8);// 0.66 MB
  float* px1  = (float*)carve((size_t)2 * NDET * 4);
  float* py1  = (float*)carve((size_t)2 * NDET * 4);
  float* px2  = (float*)carve((size_t)2 * NDET * 4);
  float* py2  = (float*)carve((size_t)2 * NDET * 4);
  float* psc  = (float*)carve((size_t)2 * NDET * 4);
  int*   plab = (int*)carve((size_t)2 * NDET * 4);
  int*   pval = (int*)carve((size_t)2 * NDET * 4);
  float* ssc  = (float*)carve((size_t)2 * NDET * 4);
  int*   sval = (int*)carve((size_t)2 * NDET * 4);
  float* ox1  = (float*)carve((size_t)2 * NDET * 4);
  float* oy1  = (float*)carve((size_t)2 * NDET * 4);
  float* ox2  = (float*)carve((size_t)2 * NDET * 4);
  float* oy2  = (float*)carve((size_t)2 * NDET * 4);
  float* oarea= (float*)carve((size_t)2 * NDET * 4);
  u64* mask   = (u64*)carve((size_t)2 * NDET * NW * 8);// 4.98 MB
  u64* rowAnyA= (u64*)carve((size_t)2 * NDET * 8);     // 71 KB
  u32* rowAnyB= (u32*)carve((size_t)2 * NDET * 4);     // 36 KB (total ~11.1 MB)
  float* out  = (float*)d_out;

  // k_scan dynamic LDS: rowA (NDET u64) + rowB (NDET u8) + remLo/remHi (NW u32 each)
  const size_t scan_lds = (size_t)NDET * 8 + (size_t)NDET + (size_t)NW * 4 * 2 + 64;

  hipLaunchKernelGGL(k_zero,       dim3(2560), dim3(256), 0, stream,
                     hist, cnt, rowAnyA, rowAnyB);
  hipLaunchKernelGGL(k_keys_hist,  dim3(1067), dim3(256), 0, stream, p, keyb, hist);
  hipLaunchKernelGGL(k_select,     dim3(10),   dim3(256), 0, stream, hist, cut);
  hipLaunchKernelGGL(k_gather,     dim3(1067), dim3(256), 0, stream, keyb, cut, cnt, cand);
  hipLaunchKernelGGL(k_sortdecode, dim3(10),   dim3(1024), 65536, stream,
                     p, cand, cnt, px1, py1, px2, py2, psc, plab, pval);
  hipLaunchKernelGGL(k_globalsort, dim3(2),    dim3(1024), 65536, stream,
                     px1, py1, px2, py2, psc, plab, pval, out, ssc, sval,
                     ox1, oy1, ox2, oy2, oarea);
  hipLaunchKernelGGL(k_mask,       dim3(NW, NW, 2), dim3(64), 0, stream,
                     ox1, oy1, ox2, oy2, oarea, mask, rowAnyA, rowAnyB);
  hipLaunchKernelGGL(k_scan,       dim3(2),    dim3(1024), scan_lds, stream,
                     mask, rowAnyA, rowAnyB, ssc, sval, out);
}

// Round 13
// 434.888 us; speedup vs baseline: 4.5887x; 1.2433x over previous
//
#include <hip/hip_runtime.h>
#include <math.h>

typedef unsigned long long u64;
typedef unsigned int u32;

#define TOTE      273024      // 2 * 136512 score elements
#define BTOT      136512
#define NDET      4448        // 1000*4 + 448
#define NW        70          // ceil(4448/64)
#define SC_BASE   35584       // 2*4448*4
#define LAB_BASE  44480
#define KEEP_BASE 53376
#define CAND_CAP  8192

struct Ptrs {
  const float* loc[5];
  const float* cls[5];
  const float* box[5];
  const float* ctr[5];
};

__constant__ int c_HW[5]  = {12800, 3200, 800, 208, 56};
__constant__ int c_K[5]   = {1000, 1000, 1000, 1000, 448};
__constant__ int c_OFF[5] = {0, 1000, 2000, 3000, 4000};

// XLA LogisticExpander: logistic(x) = 1 / (1 + exp(-x)).
// expf() == __ocml_exp_f32 on ROCm -> bit-identical to the jax-rocm reference.
// VERIFIED rounds 3, 10, 12: absmax == 0.0.
__device__ __forceinline__ float ref_sigmoid(float x) {
#pragma clang fp contract(off)
  float e = expf(-x);
  return 1.0f / (1.0f + e);
}

__device__ __forceinline__ u32 ordf(float v) {
  u32 b = __float_as_uint(v);
  return (b & 0x80000000u) ? ~b : (b | 0x80000000u);
}
__device__ __forceinline__ float unordf(u32 o) {
  u32 b = (o & 0x80000000u) ? (o ^ 0x80000000u) : ~o;
  return __uint_as_float(b);
}

__device__ __forceinline__ u64 shfl64(u64 v, int src) {
  int lo = __shfl((int)(u32)(v & 0xFFFFFFFFull), src, 64);
  int hi = __shfl((int)(u32)(v >> 32), src, 64);
  return ((u64)(u32)hi << 32) | (u32)lo;
}

// element id -> (segment = b*5+l, local flat index f within segment)
__device__ __forceinline__ int seg_decompose(int e, int& f) {
  int b = 0;
  if (e >= BTOT) { b = 1; e -= BTOT; }
  int l, base;
  if      (e < 102400) { l = 0; base = 0; }
  else if (e < 128000) { l = 1; base = 102400; }
  else if (e < 134400) { l = 2; base = 128000; }
  else if (e < 136064) { l = 3; base = 134400; }
  else                 { l = 4; base = 136064; }
  f = e - base;
  return b * 5 + l;
}

__global__ __launch_bounds__(256) void k_zero(u32* hist, u32* cnt,
                                              u64* rowAnyA, u32* rowAnyB) {
  int i = blockIdx.x * 256 + threadIdx.x;
  if (i < 10 * 65536) hist[i] = 0u;
  if (i < 16) cnt[i] = 0u;
  if (i < 2 * NDET) { rowAnyA[i] = 0ull; rowAnyB[i] = 0u; }
}

__global__ __launch_bounds__(256) void k_keys_hist(Ptrs p, u64* keyb, u32* hist) {
#pragma clang fp contract(off)
  int e = blockIdx.x * 256 + threadIdx.x;
  if (e >= TOTE) return;
  int f; int s = seg_decompose(e, f);
  int b = s / 5, l = s % 5;
  int hw = f >> 3, c = f & 7;
  int HW = c_HW[l];
  float cp = ref_sigmoid(p.cls[l][(size_t)(b * 8 + c) * HW + hw]);
  float flatv = -1.0f;
  if (cp > 0.05f) {
    float tp = ref_sigmoid(p.ctr[l][(size_t)b * HW + hw]);
    flatv = cp * tp;   // score = cls_p * ctr_p
  }
  u32 o = ordf(flatv);
  keyb[e] = ((u64)o << 32) | (0xFFFFFFFFu - (u32)f);  // desc value, asc idx
  atomicAdd(&hist[(s << 16) + (o >> 16)], 1u);
}

// R10: uint4 vectorized per-thread sums (latency-bound stride loads /4),
// and the chosen chunk's bins staged to LDS cooperatively before the serial
// tid0 scan (was: 256 serially-dependent global loads).
__global__ __launch_bounds__(256) void k_select(const u32* hist, u32* cut) {
  __shared__ u32 cs[256];
  __shared__ u32 binbuf[256];
  __shared__ int sh_ch;
  __shared__ u32 sh_cum;
  int s = blockIdx.x, tid = threadIdx.x;
  const u32* h = hist + (s << 16);
  const uint4* h4 = (const uint4*)(h + tid * 256);
  u32 sum = 0;
  for (int i = 0; i < 64; ++i) {
    uint4 v = h4[i];
    sum += v.x + v.y + v.z + v.w;
  }
  cs[tid] = sum;
  __syncthreads();
  if (tid == 0) {
    u32 k = (u32)c_K[s % 5];
    u32 cum = 0; int ch = 0;
    for (int c2 = 255; c2 >= 0; --c2) {
      if (cum + cs[c2] >= k) { ch = c2; break; }
      cum += cs[c2];
    }
    sh_ch = ch; sh_cum = cum;
  }
  __syncthreads();
  binbuf[tid] = h[sh_ch * 256 + tid];   // coalesced stage of chosen chunk
  __syncthreads();
  if (tid == 0) {
    u32 k = (u32)c_K[s % 5];
    u32 cum = sh_cum; int ch = sh_ch; int bstar = ch * 256;
    for (int bb = 255; bb >= 0; --bb) {
      u32 c2 = binbuf[bb];
      if (cum + c2 >= k) { bstar = ch * 256 + bb; break; }
      cum += c2;
    }
    cut[s] = (u32)bstar;
  }
}

__global__ __launch_bounds__(256) void k_gather(const u64* keyb, const u32* cut,
                                                u32* cnt, u64* cand) {
  int e = blockIdx.x * 256 + threadIdx.x;
  if (e >= TOTE) return;
  int f; int s = seg_decompose(e, f);
  u64 key = keyb[e];
  u32 bin = (u32)(key >> 48);
  if (bin >= cut[s]) {
    u32 pos = atomicAdd(&cnt[s], 1u);
    if (pos < CAND_CAP) cand[((size_t)s << 13) + pos] = key;
  }
}

// Bitonic sort, descending, over m (power of 2) elements.
__device__ __forceinline__ void bitonic_desc(u64* sb, int tid, int nthr, u32 m) {
  for (u32 k = 2; k <= m; k <<= 1) {
    for (u32 j = k >> 1; j > 0; j >>= 1) {
      __syncthreads();
      for (u32 i = (u32)tid; i < m; i += (u32)nthr) {
        u32 l = i ^ j;
        if (l > i) {
          u64 a = sb[i], b = sb[l];
          bool up = ((i & k) != 0);           // inverted -> final descending
          if (up ? (a > b) : (a < b)) { sb[i] = b; sb[l] = a; }
        }
      }
    }
  }
  __syncthreads();
}

extern __shared__ u64 sbuf[];

__global__ __launch_bounds__(1024) void k_sortdecode(Ptrs p, const u64* cand, const u32* cnt,
                             float* px1, float* py1, float* px2, float* py2,
                             float* psc, int* plab, int* pval) {
#pragma clang fp contract(off)
  int s = blockIdx.x, tid = threadIdx.x;
  int b = s / 5, l = s % 5;
  int n = (int)cnt[s]; if (n > CAND_CAP) n = CAND_CAP;
  // R10: sort only next_pow2(n) slots (cutoff construction guarantees n >= k,
  // so the first k sorted entries are identical to the full-8192 sort; zero
  // pads sort last since every real key has nonzero value bits).
  u32 m = 64; while ((int)m < n) m <<= 1;
  for (int i = tid; i < (int)m; i += 1024)
    sbuf[i] = (i < n) ? cand[((size_t)s << 13) + i] : 0ull;
  __syncthreads();
  bitonic_desc(sbuf, tid, 1024, m);
  int k = c_K[l], off = c_OFF[l], HW = c_HW[l];
  for (int r = tid; r < k; r += 1024) {
    int pos = b * NDET + off + r;
    if (r < n) {
      u64 key = sbuf[r];
      float val = unordf((u32)(key >> 32));
      u32 f = 0xFFFFFFFFu - (u32)(key & 0xFFFFFFFFull);
      int hw = (int)(f >> 3), c = (int)(f & 7);
      float x = p.loc[l][hw * 2 + 0], y = p.loc[l][hw * 2 + 1];
      float b0 = p.box[l][(size_t)(b * 4 + 0) * HW + hw];
      float b1 = p.box[l][(size_t)(b * 4 + 1) * HW + hw];
      float b2 = p.box[l][(size_t)(b * 4 + 2) * HW + hw];
      float b3 = p.box[l][(size_t)(b * 4 + 3) * HW + hw];
      float d0 = x - b0, d1 = y - b1, d2 = x + b2, d3 = y + b3;
      float x1 = fminf(fmaxf(d0, 0.0f), 1023.0f);   // clip to [0, W-1]
      float y1 = fminf(fmaxf(d1, 0.0f), 799.0f);    // clip to [0, H-1]
      float x2 = fminf(fmaxf(d2, 0.0f), 1023.0f);
      float y2 = fminf(fmaxf(d3, 0.0f), 799.0f);
      int valid = (val > 0.0f) ? 1 : 0;
      if (!((x2 - x1 + 1.0f) >= 0.0f) || !((y2 - y1 + 1.0f) >= 0.0f)) valid = 0;
      float sc = valid ? sqrtf(val) : 0.0f;
      px1[pos] = x1; py1[pos] = y1; px2[pos] = x2; py2[pos] = y2;
      psc[pos] = sc; plab[pos] = c + 1; pval[pos] = valid;
    } else {
      px1[pos] = 0.f; py1[pos] = 0.f; px2[pos] = 0.f; py2[pos] = 0.f;
      psc[pos] = 0.f; plab[pos] = 1; pval[pos] = 0;
    }
  }
}

// R12: merge-rank instead of bitonic sort. The per-batch array is 5 sorted
// segments (each level's output is sorted desc by key=(ordf(v)<<32)|(~i):
// v non-increasing in r, padding v=-1 at the tail, i=off+r increasing).
// Stable global argsort position of element i = #{keys > key_i} = sum of
// per-segment binary-search counts (own segment's count = own position).
// Keys unique (idx tie-break) -> exact permutation == jnp stable argsort.
__global__ __launch_bounds__(1024) void k_globalsort(const float* px1, const float* py1,
                             const float* px2, const float* py2,
                             const float* psc, const int* plab, const int* pval,
                             float* out, float* ssc, int* sval,
                             float* ox1, float* oy1, float* ox2, float* oy2, float* oarea) {
#pragma clang fp contract(off)
  int b = blockIdx.x, tid = threadIdx.x;
  u64* karr = sbuf;                         // NDET keys (35584 B LDS)
  for (int i = tid; i < NDET; i += 1024) {
    int g = b * NDET + i;
    float v = pval[g] ? psc[g] : -1.0f;     // argsort(-where(valid, sc, -1)), stable
    karr[i] = ((u64)ordf(v) << 32) | (0xFFFFFFFFu - (u32)i);
  }
  __syncthreads();
  for (int i = tid; i < NDET; i += 1024) {
    u64 my = karr[i];
    int rank = 0;
#pragma unroll
    for (int l = 0; l < 5; ++l) {
      int lo = c_OFF[l], hi = c_OFF[l] + c_K[l];
      while (lo < hi) {                     // first idx with key <= my (desc array)
        int mid = (lo + hi) >> 1;
        if (karr[mid] > my) lo = mid + 1; else hi = mid;
      }
      rank += lo - c_OFF[l];
    }
    int src = b * NDET + i, dst = b * NDET + rank;
    float x1 = px1[src], y1 = py1[src], x2 = px2[src], y2 = py2[src];
    out[(size_t)dst * 4 + 0] = x1;
    out[(size_t)dst * 4 + 1] = y1;
    out[(size_t)dst * 4 + 2] = x2;
    out[(size_t)dst * 4 + 3] = y2;
    float labf = (float)plab[src];
    out[LAB_BASE + dst] = labf;
    ssc[dst] = psc[src];
    sval[dst] = pval[src];
    float a1 = x1 + labf * 4096.0f;   // bo = boxes + label*CLASS_OFFSET (no fma!)
    float c1 = y1 + labf * 4096.0f;
    float a2 = x2 + labf * 4096.0f;
    float c2 = y2 + labf * 4096.0f;
    ox1[dst] = a1; oy1[dst] = c1; ox2[dst] = a2; oy2[dst] = c2;
    oarea[dst] = (a2 - a1) * (c2 - c1);
  }
}

__global__ __launch_bounds__(64) void k_mask(const float* ox1, const float* oy1,
                       const float* ox2, const float* oy2,
                       const float* oarea, u64* mask,
                       u64* rowAnyA, u32* rowAnyB) {
#pragma clang fp contract(off)
  int w = blockIdx.x, ti = blockIdx.y, b = blockIdx.z;
  if (w < ti) return;                       // j <= i tiles never read
  int lane = threadIdx.x;
  __shared__ float cx1[64], cy1[64], cx2[64], cy2[64], car[64];
  int j0 = w * 64;
  int j = j0 + lane;
  if (j < NDET) {
    int g = b * NDET + j;
    cx1[lane] = ox1[g]; cy1[lane] = oy1[g];
    cx2[lane] = ox2[g]; cy2[lane] = oy2[g];
    car[lane] = oarea[g];
  }
  __syncthreads();
  int i = ti * 64 + lane;
  if (i >= NDET) return;
  int g = b * NDET + i;
  float rx1 = ox1[g], ry1 = oy1[g], rx2 = ox2[g], ry2 = oy2[g], ra = oarea[g];
  u64 m = 0ull;
  int jmax = NDET - j0; if (jmax > 64) jmax = 64;
  for (int jj = 0; jj < jmax; ++jj) {
    int jg = j0 + jj;
    if (jg > i) {
      float xx1 = fmaxf(rx1, cx1[jj]);
      float yy1 = fmaxf(ry1, cy1[jj]);
      float xx2 = fminf(rx2, cx2[jj]);
      float yy2 = fminf(ry2, cy2[jj]);
      float iw = fmaxf(xx2 - xx1, 0.0f);
      float ih = fmaxf(yy2 - yy1, 0.0f);
      float inter = iw * ih;
      float iou = inter / (((ra + car[jj]) - inter) + 1e-9f);
      if (iou > 0.6f) m |= (1ull << jj);
    }
  }
  mask[((size_t)b * NDET + i) * NW + w] = m;
  if (m) {   // sparse summary: bit w of row i's nonzero-word bitmap
    if (w < 64) atomicOr(&rowAnyA[b * NDET + i], 1ull << w);
    else        atomicOr(&rowAnyB[b * NDET + i], 1u << (w - 64));
  }
}

// Sparsity-directed greedy scan. R10: 1024 threads — init/output loops get
// 16x TLP; the inherently serial chunk loop runs on wave 0 only, other waves
// wait at the per-chunk barrier.
__global__ __launch_bounds__(1024) void k_scan(const u64* mask,
                                               const u64* rowAnyA, const u32* rowAnyB,
                                               const float* ssc, const int* sval,
                                               float* out) {
  int b = blockIdx.x;
  int tid = threadIdx.x;
  int lane = tid & 63;
  int wid = tid >> 6;                       // 16 waves
  __shared__ float sh_kth;
  __shared__ int sh_nd;
  u64* rowA = sbuf;                                   // NDET u64  (35584 B)
  unsigned char* rowB = (unsigned char*)(sbuf + NDET);// NDET u8   (4448 B)
  u32* remLo = (u32*)(rowB + NDET);                   // NW u32
  u32* remHi = remLo + NW;                            // NW u32

  for (int i = tid; i < NDET; i += 1024) {
    rowA[i] = rowAnyA[b * NDET + i];
    rowB[i] = (unsigned char)rowAnyB[b * NDET + i];
  }
  for (int w = wid; w < NW; w += 16) {                // rem init: one word per wave
    int i = w * 64 + lane;
    u64 bb = __ballot((i < NDET) && (sval[b * NDET + i] != 0));
    if (lane == 0) {
      u64 rm = ~bb;                                   // removed = ~valid
      remLo[w] = (u32)rm; remHi[w] = (u32)(rm >> 32);
    }
  }
  __syncthreads();

  for (int c = 0; c < NW; ++c) {
    u64 rem = ((u64)remHi[c] << 32) | remLo[c];
    u64 alive = ~rem;
    if (alive == 0ull) continue;                      // uniform skip (LDS value)
    if (tid < 64) {                                   // wave 0 does the serial work
      int row = c * 64 + lane;
      bool inr = (row < NDET);
      u64 rA = inr ? rowA[row] : 0ull;
      u32 rB = inr ? (u32)rowB[row] : 0u;
      bool hasDiag = (c < 64) ? (((rA >> c) & 1ull) != 0ull)
                              : (((rB >> (c - 64)) & 1u) != 0u);
      u64 anyD = __ballot(hasDiag);
      if (anyD & alive) {                             // intra-chunk suppression exists
        u64 diag = hasDiag ? mask[((size_t)b * NDET + row) * NW + c] : 0ull;
        u64 a2 = alive;
        u64 it = anyD;                                // only bits that can suppress
        while (it) {
          int bit = __ffsll(it) - 1; it &= it - 1ull;
          if ((a2 >> bit) & 1ull) {                   // still kept at its turn
            u64 dw = shfl64(diag, bit);
            a2 &= ~dw;
          }
        }
        if (lane == 0) {
          u64 nr2 = ~a2;
          remLo[c] = (u32)nr2; remHi[c] = (u32)(nr2 >> 32);
        }
        alive = a2;
      }
      // forward apply: each surviving lane walks its own row's nonzero words > c
      if (inr && ((alive >> lane) & 1ull)) {
        u64 fa; u32 fb;
        if (c < 64) { fa = rA & ~((2ull << c) - 1ull); fb = rB; }
        else        { fa = 0ull; fb = rB & ~((2u << (c - 64)) - 1u); }
        while (fa) {
          int w2 = __ffsll(fa) - 1; fa &= fa - 1ull;
          u64 m = mask[((size_t)b * NDET + row) * NW + w2];
          u32 lo = (u32)m, hi = (u32)(m >> 32);
          if (lo) atomicOr(&remLo[w2], lo);
          if (hi) atomicOr(&remHi[w2], hi);
        }
        while (fb) {
          int w2 = 64 + __ffs(fb) - 1; fb &= fb - 1u;
          u64 m = mask[((size_t)b * NDET + row) * NW + w2];
          u32 lo = (u32)m, hi = (u32)(m >> 32);
          if (lo) atomicOr(&remLo[w2], lo);
          if (hi) atomicOr(&remHi[w2], hi);
        }
      }
    }
    __syncthreads();                                  // publish to next chunk
  }

  if (tid == 0) {
    int nd = 0;
    for (int w = 0; w < NW; ++w)
      nd += __popcll(~(((u64)remHi[w] << 32) | remLo[w]));
    float kth = 0.0f;
    if (nd > 100) {                          // kth = 100th kept score (desc order)
      int cum = 0;
      for (int w = 0; w < NW; ++w) {
        u64 kw = ~(((u64)remHi[w] << 32) | remLo[w]);
        int pc = __popcll(kw);
        if (cum + pc >= 100) {
          int need = 100 - cum;
          u64 mm = kw; int bp = 0;
          for (int t = 0; t < need; ++t) { bp = __ffsll(mm) - 1; mm &= mm - 1ull; }
          kth = ssc[b * NDET + w * 64 + bp];
          break;
        }
        cum += pc;
      }
    }
    sh_nd = nd; sh_kth = kth;
  }
  __syncthreads();
  int nd = sh_nd; float kth = sh_kth;
  for (int i = tid; i < NDET; i += 1024) {
    bool kp = ((~(((u64)remHi[i >> 6] << 32) | remLo[i >> 6]) >> (i & 63)) & 1ull) != 0ull;
    float sc = ssc[b * NDET + i];
    bool kf = kp && (nd > 100 ? (sc >= kth) : true);
    out[SC_BASE + b * NDET + i] = kf ? sc : 0.0f;
    out[KEEP_BASE + b * NDET + i] = kf ? 1.0f : 0.0f;
  }
}

extern "C" void kernel_launch(void* const* d_in, const int* in_sizes, int n_in,
                              void* d_out, int out_size, void* d_ws, size_t ws_size,
                              hipStream_t stream) {
  (void)n_in; (void)out_size; (void)ws_size;
  Ptrs p;
  // setup_inputs() dict order is interleaved (loc0,cls0,box0,ctr0,loc1,...);
  // detect signature-grouped order defensively via in_sizes[1].
  bool interleaved = (in_sizes[1] == 204800);
  for (int l = 0; l < 5; ++l) {
    if (interleaved) {
      p.loc[l] = (const float*)d_in[4 * l + 0];
      p.cls[l] = (const float*)d_in[4 * l + 1];
      p.box[l] = (const float*)d_in[4 * l + 2];
      p.ctr[l] = (const float*)d_in[4 * l + 3];
    } else {
      p.loc[l] = (const float*)d_in[l];
      p.cls[l] = (const float*)d_in[5 + l];
      p.box[l] = (const float*)d_in[10 + l];
      p.ctr[l] = (const float*)d_in[15 + l];
    }
  }

  char* base = (char*)d_ws;
  size_t o = 0;
  auto carve = [&](size_t bytes) -> void* {
    void* r = base + o;
    o += (bytes + 511) & ~(size_t)511;
    return r;
  };
  u32* hist   = (u32*)carve((size_t)10 * 65536 * 4);   // 2.62 MB
  u32* cut    = (u32*)carve(64);
  u32* cnt    = (u32*)carve(64);
  u64* keyb   = (u64*)carve((size_t)TOTE * 8);         // 2.18 MB
  u64* cand   = (u64*)carve((size_t)10 * CAND_CAP * 8);// 0.66 MB
  float* px1  = (float*)carve((size_t)2 * NDET * 4);
  float* py1  = (float*)carve((size_t)2 * NDET * 4);
  float* px2  = (float*)carve((size_t)2 * NDET * 4);
  float* py2  = (float*)carve((size_t)2 * NDET * 4);
  float* psc  = (float*)carve((size_t)2 * NDET * 4);
  int*   plab = (int*)carve((size_t)2 * NDET * 4);
  int*   pval = (int*)carve((size_t)2 * NDET * 4);
  float* ssc  = (float*)carve((size_t)2 * NDET * 4);
  int*   sval = (int*)carve((size_t)2 * NDET * 4);
  float* ox1  = (float*)carve((size_t)2 * NDET * 4);
  float* oy1  = (float*)carve((size_t)2 * NDET * 4);
  float* ox2  = (float*)carve((size_t)2 * NDET * 4);
  float* oy2  = (float*)carve((size_t)2 * NDET * 4);
  float* oarea= (float*)carve((size_t)2 * NDET * 4);
  u64* mask   = (u64*)carve((size_t)2 * NDET * NW * 8);// 4.98 MB
  u64* rowAnyA= (u64*)carve((size_t)2 * NDET * 8);     // 71 KB
  u32* rowAnyB= (u32*)carve((size_t)2 * NDET * 4);     // 36 KB (total ~11.1 MB)
  float* out  = (float*)d_out;

  // k_scan dynamic LDS: rowA (NDET u64) + rowB (NDET u8) + remLo/remHi (NW u32 each)
  const size_t scan_lds = (size_t)NDET * 8 + (size_t)NDET + (size_t)NW * 4 * 2 + 64;
  // k_globalsort dynamic LDS: NDET keys
  const size_t gs_lds = (size_t)NDET * 8;

  hipLaunchKernelGGL(k_zero,       dim3(2560), dim3(256), 0, stream,
                     hist, cnt, rowAnyA, rowAnyB);
  hipLaunchKernelGGL(k_keys_hist,  dim3(1067), dim3(256), 0, stream, p, keyb, hist);
  hipLaunchKernelGGL(k_select,     dim3(10),   dim3(256), 0, stream, hist, cut);
  hipLaunchKernelGGL(k_gather,     dim3(1067), dim3(256), 0, stream, keyb, cut, cnt, cand);
  hipLaunchKernelGGL(k_sortdecode, dim3(10),   dim3(1024), 65536, stream,
                     p, cand, cnt, px1, py1, px2, py2, psc, plab, pval);
  hipLaunchKernelGGL(k_globalsort, dim3(2),    dim3(1024), gs_lds, stream,
                     px1, py1, px2, py2, psc, plab, pval, out, ssc, sval,
                     ox1, oy1, ox2, oy2, oarea);
  hipLaunchKernelGGL(k_mask,       dim3(NW, NW, 2), dim3(64), 0, stream,
                     ox1, oy1, ox2, oy2, oarea, mask, rowAnyA, rowAnyB);
  hipLaunchKernelGGL(k_scan,       dim3(2),    dim3(1024), scan_lds, stream,
                     mask, rowAnyA, rowAnyB, ssc, sval, out);
}